// Round 3
// baseline (271.271 us; speedup 1.0000x reference)
//
#include <hip/hip_runtime.h>
#include <hip/hip_fp16.h>

typedef _Float16 half8 __attribute__((ext_vector_type(8)));
typedef float    floatx4 __attribute__((ext_vector_type(4)));

#define MFMA16(a, b, c) __builtin_amdgcn_mfma_f32_16x16x32_f16((a), (b), (c), 0, 0, 0)

constexpr int T_ = 2048;
constexpr int D_ = 1024;
constexpr int NB = 4;

__device__ __forceinline__ half8 cvt8(floatx4 a, floatx4 b) {
  half8 h;
  h[0] = (_Float16)a[0]; h[1] = (_Float16)a[1]; h[2] = (_Float16)a[2]; h[3] = (_Float16)a[3];
  h[4] = (_Float16)b[0]; h[5] = (_Float16)b[1]; h[6] = (_Float16)b[2]; h[7] = (_Float16)b[3];
  return h;
}

// ---- prep: cast V->f16 (Vh) and build transposed VhT[D][T] ----
template <int MODE>
__global__ __launch_bounds__(256) void prep(const float* __restrict__ V,
                                            _Float16* __restrict__ VhT,
                                            _Float16* __restrict__ Vh) {
  __shared__ _Float16 tile[64][65];  // +1 pad: transpose reads 2-way max (free)
  const int bid = blockIdx.x;
  const int b = bid & 3;
  const int tt = (bid >> 2) & 31;   // 64-row t-tile
  const int dd = bid >> 7;          // 64-col d-tile
  const float* Vb = V + ((size_t)b * T_ + tt * 64) * D_ + dd * 64;
#pragma unroll
  for (int k = 0; k < 16; ++k) {
    const int e = k * 256 + threadIdx.x;
    const int r = e >> 6, c = e & 63;
    const _Float16 h = (_Float16)Vb[(size_t)r * D_ + c];
    tile[r][c] = h;
    if (MODE == 2) Vh[((size_t)b * T_ + tt * 64 + r) * D_ + dd * 64 + c] = h;
  }
  __syncthreads();
#pragma unroll
  for (int k = 0; k < 16; ++k) {
    const int e = k * 256 + threadIdx.x;
    const int dr = e >> 6, tc = e & 63;
    VhT[((size_t)b * D_ + dd * 64 + dr) * T_ + tt * 64 + tc] = tile[tc][dr];
  }
}

template <int MODE>
__device__ __forceinline__ half8 loadA(const _Float16* __restrict__ Vhb,
                                       const float* __restrict__ Vb, int row, int col) {
  if (MODE == 2) return *(const half8*)(Vhb + (size_t)row * D_ + col);
  const float* p = Vb + (size_t)row * D_ + col;
  return cvt8(*(const floatx4*)p, *(const floatx4*)(p + 4));
}

template <int MODE>
__device__ __forceinline__ half8 loadB(const _Float16* __restrict__ VhTb,
                                       const float* __restrict__ Vb, int dim, int kv) {
  if (MODE >= 1) return *(const half8*)(VhTb + (size_t)dim * T_ + kv);
  half8 h;  // emergency gather
#pragma unroll
  for (int j = 0; j < 8; ++j) h[j] = (_Float16)Vb[(size_t)(kv + j) * D_ + dim];
  return h;
}

// ---- causal flash attention, K=V, Br=16, Bc=32, reg-double-buffered frags ----
template <int MODE>
__global__ __launch_bounds__(512) void attn(const float* __restrict__ Qg,
                                            const float* __restrict__ Vg,
                                            const _Float16* __restrict__ VhTg,
                                            const _Float16* __restrict__ Vhg,
                                            float* __restrict__ Og) {
  __shared__ float RED[8][16][36];   // stride 36: conflict-free read pattern
  __shared__ _Float16 Psh[16][32];
  __shared__ float AL[16];
  __shared__ float LL[16];

  const int tid = threadIdx.x;
  const int w = tid >> 6, l = tid & 63, l15 = l & 15, hi = l >> 4;
  const int koff = hi * 8;
  const int row_sm = 2 * w + (l >> 5);
  const int kv_sm = l & 31;

  // static balanced schedule with batch->XCD affinity:
  // bid%8 -> XCD; batch = bid&3 pins each batch to an XCD pair (L2 locality).
  const int batch = blockIdx.x & 3;
  const int pp = (int)(blockIdx.x >> 2);          // 0..63

  const float* Qb = Qg + (size_t)batch * T_ * D_;
  const float* Vb = Vg + (size_t)batch * T_ * D_;
  const _Float16* VhTb = (MODE >= 1) ? VhTg + (size_t)batch * T_ * D_ : (const _Float16*)nullptr;
  const _Float16* Vhb  = (MODE == 2) ? Vhg  + (size_t)batch * T_ * D_ : (const _Float16*)nullptr;

  for (int it = 0; it < 2; ++it) {
    const int s = it ? pp : (127 - pp);           // long strip first; pair-sum const
    const int qbase = s * 16;
    const int ntiles = ((qbase + 15) >> 5) + 1;

    half8 qfrag[4];
#pragma unroll
    for (int c = 0; c < 4; ++c) {
      const float* p = Qb + (size_t)(qbase + l15) * D_ + w * 128 + c * 32 + koff;
      qfrag[c] = cvt8(*(const floatx4*)p, *(const floatx4*)(p + 4));
    }
    floatx4 accO[8];
#pragma unroll
    for (int f = 0; f < 8; ++f) accO[f] = (floatx4){0.f, 0.f, 0.f, 0.f};
    float m_run = -1e30f, l_run = 0.f;

    half8 Aa0[4], Aa1[4], Ba[8], Ab0[4], Ab1[4], Bb[8];

    auto LOADT = [&](half8 (&A0)[4], half8 (&A1)[4], half8 (&Bv)[8], const int kv0) {
      int ra0 = kv0 + l15;      if (ra0 > T_ - 1) ra0 = T_ - 1;   // clamp: prefetch
      int ra1 = kv0 + 16 + l15; if (ra1 > T_ - 1) ra1 = T_ - 1;   // past end is
      int kvb = kv0 + koff;     if (kvb > T_ - 8) kvb = T_ - 8;   // never consumed
#pragma unroll
      for (int c = 0; c < 4; ++c) {
        const int col = w * 128 + c * 32 + koff;
        A0[c] = loadA<MODE>(Vhb, Vb, ra0, col);
        A1[c] = loadA<MODE>(Vhb, Vb, ra1, col);
      }
#pragma unroll
      for (int f = 0; f < 8; ++f)
        Bv[f] = loadB<MODE>(VhTb, Vb, w * 128 + f * 16 + l15, kvb);
    };

    auto STEP = [&](half8 (&A0)[4], half8 (&A1)[4], half8 (&Bv)[8],
                    half8 (&N0)[4], half8 (&N1)[4], half8 (&NBv)[8], const int t) {
      // issue next tile's 16 loads first: latency hides under QK+softmax+PV
      LOADT(N0, N1, NBv, t * 32 + 32);

      floatx4 sf0 = {0.f, 0.f, 0.f, 0.f}, sf1 = {0.f, 0.f, 0.f, 0.f};
#pragma unroll
      for (int c = 0; c < 4; ++c) {
        sf0 = MFMA16(A0[c], qfrag[c], sf0);
        sf1 = MFMA16(A1[c], qfrag[c], sf1);
      }
      *(floatx4*)&RED[w][l15][4 * hi]      = sf0;
      *(floatx4*)&RED[w][l15][16 + 4 * hi] = sf1;
      __syncthreads();

      {  // wave-parallel online softmax: thread owns (row_sm, kv_sm)
        float sv = 0.f;
#pragma unroll
        for (int ww = 0; ww < 8; ++ww) sv += RED[ww][row_sm][kv_sm];
        const int col = t * 32 + kv_sm;
        if (col > qbase + row_sm) sv = -1e30f;   // causal mask
        float mt = sv;
#pragma unroll
        for (int off = 16; off; off >>= 1) mt = fmaxf(mt, __shfl_xor(mt, off));
        const float mnew = fmaxf(m_run, mt);
        const float al = __expf(m_run - mnew);
        const float p  = __expf(sv - mnew);
        float rs = p;
#pragma unroll
        for (int off = 16; off; off >>= 1) rs += __shfl_xor(rs, off);
        l_run = l_run * al + rs;
        m_run = mnew;
        Psh[row_sm][kv_sm] = (_Float16)p;
        if (kv_sm == 0) AL[row_sm] = al;
      }
      __syncthreads();

      // PV: O[16 q][128-dim slice] += P[16][32] * V[32][dims]
      const half8 pa = *(const half8*)&Psh[l15][koff];
      float ar[4];
#pragma unroll
      for (int r = 0; r < 4; ++r) ar[r] = AL[4 * hi + r];
#pragma unroll
      for (int f = 0; f < 8; ++f) {
#pragma unroll
        for (int r = 0; r < 4; ++r) accO[f][r] *= ar[r];
        accO[f] = MFMA16(pa, Bv[f], accO[f]);
      }
    };

    LOADT(Aa0, Aa1, Ba, 0);
    int t = 0;
    for (;;) {  // ping-pong: no runtime-indexed reg arrays (scratch hazard)
      STEP(Aa0, Aa1, Ba, Ab0, Ab1, Bb, t);
      if (++t == ntiles) break;
      STEP(Ab0, Ab1, Bb, Aa0, Aa1, Ba, t);
      if (++t == ntiles) break;
    }

    if (kv_sm == 0) LL[row_sm] = l_run;
    __syncthreads();
    float inv[4];
#pragma unroll
    for (int r = 0; r < 4; ++r) inv[r] = 1.0f / LL[4 * hi + r];
    float* Ob = Og + ((size_t)batch * T_ + qbase) * D_;
#pragma unroll
    for (int f = 0; f < 8; ++f) {
      const int dim = w * 128 + f * 16 + l15;
#pragma unroll
      for (int r = 0; r < 4; ++r)
        Ob[(size_t)(4 * hi + r) * D_ + dim] = accO[f][r] * inv[r];
    }
    __syncthreads();  // protect LL/Psh/AL before next item
  }
}

extern "C" void kernel_launch(void* const* d_in, const int* in_sizes, int n_in,
                              void* d_out, int out_size, void* d_ws, size_t ws_size,
                              hipStream_t stream) {
  const float* q = (const float*)d_in[0];
  const float* v = (const float*)d_in[1];
  float* out = (float*)d_out;
  const size_t NE = (size_t)NB * T_ * D_;        // 8388608 elems
  const size_t HB = NE * sizeof(_Float16);       // 16 MiB

  if (ws_size >= 2 * HB) {
    _Float16* vt = (_Float16*)d_ws;
    _Float16* vh = (_Float16*)((char*)d_ws + HB);
    prep<2><<<dim3(2048), dim3(256), 0, stream>>>(v, vt, vh);
    attn<2><<<dim3(256), dim3(512), 0, stream>>>(q, v, vt, vh, out);
  } else if (ws_size >= HB) {
    _Float16* vt = (_Float16*)d_ws;
    prep<1><<<dim3(2048), dim3(256), 0, stream>>>(v, vt, nullptr);
    attn<1><<<dim3(256), dim3(512), 0, stream>>>(q, v, vt, nullptr, out);
  } else {
    attn<0><<<dim3(256), dim3(512), 0, stream>>>(q, v, nullptr, nullptr, out);
  }
}